// Round 6
// baseline (398.087 us; speedup 1.0000x reference)
//
#include <hip/hip_runtime.h>
#include <stdint.h>

#define N_ANCH 12288
#define NCLS 64
#define CHUNK 4096
#define NCHUNK 3
#define CW 64                  // words per chunk
#define SLOTW ((size_t)CHUNK * CW)   // u64s per diag slot
#define TOTW 192               // words over all anchors

typedef unsigned long long u64;
typedef unsigned int u32;

// IoU > 0.5 predicate, replicating numpy op order/rounding exactly (no FMA contraction).
__device__ __forceinline__ bool iou_gt(float4 a, float fa, float4 b, float fb) {
    float xx1 = fmaxf(a.x, b.x);
    float yy1 = fmaxf(a.y, b.y);
    float xx2 = fminf(a.z, b.z);
    float yy2 = fminf(a.w, b.w);
    float dx = fmaxf(__fsub_rn(xx2, xx1), 0.0f);
    float dy = fmaxf(__fsub_rn(yy2, yy1), 0.0f);
    float inter = __fmul_rn(dx, dy);
    float denom = __fadd_rn(__fsub_rn(__fadd_rn(fa, fb), inter), 1e-9f);
    float iou = __fdiv_rn(inter, denom);
    return iou > 0.5f;
}

// ---------------- decode: boxes, score, sortable key, area (+ zero bit arrays) ----------------
__global__ void decode_kernel(const float4* __restrict__ loc, const float* __restrict__ cls,
                              float4* __restrict__ boxes, float* __restrict__ score,
                              u32* __restrict__ key, float* __restrict__ area,
                              u64* __restrict__ zero_base) {
    int i = blockIdx.x * 256 + threadIdx.x;
    if (blockIdx.x == 0) {
        for (int k = threadIdx.x; k < 3 * TOTW; k += 256) zero_base[k] = 0ull;  // valid/removed/kept
    }
    if (i >= N_ANCH) return;
    float4 l = loc[i];
    int y = i >> 7;        // FM_W = 128
    int x = i & 127;
    float cx = (x + 0.5f) * 8.0f;   // exact
    float cy = (y + 0.5f) * 8.0f;   // exact
    float px = __fadd_rn(__fmul_rn(l.x, 32.0f), cx);
    float py = __fadd_rn(__fmul_rn(l.y, 32.0f), cy);
    float pw = __fmul_rn(expf(l.z), 32.0f);
    float ph = __fmul_rn(expf(l.w), 32.0f);
    float hx = __fmul_rn(pw, 0.5f);
    float hy = __fmul_rn(ph, 0.5f);
    float x1 = __fsub_rn(px, hx), y1 = __fsub_rn(py, hy);
    float x2 = __fadd_rn(px, hx), y2 = __fadd_rn(py, hy);
    float4 b; b.x = x1; b.y = y1; b.z = x2; b.w = y2;
    boxes[i] = b;
    area[i] = __fmul_rn(__fsub_rn(x2, x1), __fsub_rn(y2, y1));

    const float4* cr = (const float4*)(cls + (size_t)i * NCLS);
    float mx = -INFINITY;
#pragma unroll
    for (int k = 0; k < 16; ++k) {
        float4 v = cr[k];
        mx = fmaxf(mx, fmaxf(fmaxf(v.x, v.y), fmaxf(v.z, v.w)));
    }
    float s;
    if (mx >= 0.0f) {
        float e = expf(-mx);
        s = __fdiv_rn(1.0f, __fadd_rn(1.0f, e));
    } else {
        float e = expf(mx);
        s = __fdiv_rn(e, __fadd_rn(1.0f, e));
    }
    score[i] = s;
    float se = (s > 0.5f) ? s : -INFINITY;   // score_eff
    u32 u = __float_as_uint(se);
    u = (u & 0x80000000u) ? ~u : (u | 0x80000000u);   // ascending-ordered uint
    key[i] = u;
}

// ---------------- rank sort: stable descending argsort via O(N^2) rank ----------------
// 1536 blocks x 256 thr; 8 rows/block, 32 parts/row, 96 uint4 per part (covers all 12288 keys).
__global__ void rank_kernel(const u32* __restrict__ key, const float4* __restrict__ boxes,
                            const float* __restrict__ area, const float* __restrict__ score,
                            int* __restrict__ rankp, float4* __restrict__ sboxes,
                            float* __restrict__ sarea, u64* __restrict__ valid_words) {
    int tid = threadIdx.x;
    int part = tid & 31;
    int row = blockIdx.x * 8 + (tid >> 5);
    u32 ki = key[row];
    const uint4* kp = (const uint4*)key;
    int r = 0;
#pragma unroll 8
    for (int q = 0; q < 96; ++q) {           // 96*32 = 3072 uint4 = 12288 keys
        uint4 v = kp[(q << 5) + part];
        int j0 = (q << 7) + (part << 2);
        r += (int)(v.x > ki) + (int)((v.x == ki) & (j0 + 0 < row));
        r += (int)(v.y > ki) + (int)((v.y == ki) & (j0 + 1 < row));
        r += (int)(v.z > ki) + (int)((v.z == ki) & (j0 + 2 < row));
        r += (int)(v.w > ki) + (int)((v.w == ki) & (j0 + 3 < row));
    }
    r += __shfl_xor(r, 1);
    r += __shfl_xor(r, 2);
    r += __shfl_xor(r, 4);
    r += __shfl_xor(r, 8);
    r += __shfl_xor(r, 16);
    if (part == 0) {
        rankp[row] = r;
        sboxes[r] = boxes[row];
        sarea[r] = area[row];
        if (score[row] > 0.5f) atomicOr(&valid_words[r >> 6], 1ull << (r & 63));
    }
}

// ---------------- diag row helper: one sorted row vs its whole chunk ----------------
__device__ __forceinline__ void diag_row(int gi, int cb, int lane, int wv,
                                         const float4* __restrict__ sboxes,
                                         const float* __restrict__ sarea,
                                         u64* __restrict__ drow) {
    float4 bi = sboxes[gi];
    float ai = sarea[gi];
#pragma unroll
    for (int w8 = 0; w8 < 16; ++w8) {
        int w = wv * 16 + w8;
        int j = cb + (w << 6) + lane;
        bool pred = iou_gt(bi, ai, sboxes[j], sarea[j]) && (j > gi);
        u64 bits = __ballot(pred);
        if (lane == 0) drow[w] = bits;
    }
}

// all chunks in one dispatch (big-ws path): 12288 blocks
__global__ void diag_all_kernel(const float4* __restrict__ sboxes, const float* __restrict__ sarea,
                                u64* __restrict__ diag) {
    int gi = blockIdx.x;
    int c = gi >> 12;
    int li = gi & (CHUNK - 1);
    diag_row(gi, c << 12, threadIdx.x & 63, threadIdx.x >> 6,
             sboxes, sarea, diag + (size_t)c * SLOTW + (size_t)li * CW);
}

// one chunk into slot 0 (small-ws fallback): 4096 blocks
__global__ void diag_one_kernel(const float4* __restrict__ sboxes, const float* __restrict__ sarea,
                                u64* __restrict__ diag, int c) {
    int li = blockIdx.x;
    diag_row((c << 12) + li, c << 12, threadIdx.x & 63, threadIdx.x >> 6,
             sboxes, sarea, diag + (size_t)li * CW);
}

// ---------------- sequential greedy scan within one chunk (1 wave) ----------------
#define LOADROW(S, B) do { \
    const ulonglong2* rp_ = (const ulonglong2*)(dslot + (size_t)(((S) << 6) + lane) * CW); \
    _Pragma("unroll") \
    for (int p_ = 0; p_ < 32; ++p_) { ulonglong2 v_ = rp_[p_]; B[2 * p_] = v_.x; B[2 * p_ + 1] = v_.y; } \
} while (0)

#define STEP(S, BC, BN) do { \
    if ((S) + 1 < CW) LOADROW((S) + 1, BN); \
    __syncthreads(); \
    u64 W_ = state[S]; \
    u64 own_s_ = BC[S]; \
    u64 suppmask_ = __ballot(own_s_ != 0ull); \
    u64 cur_ = ~W_; \
    u64 kept_ = 0; \
    while (true) { \
        u64 m_ = cur_ & suppmask_; \
        if (m_ == 0) { kept_ |= cur_; break; } \
        int t_ = __ffsll(m_) - 1; \
        u64 below_ = (t_ == 0) ? 0ull : (cur_ & ((1ull << t_) - 1ull)); \
        kept_ |= below_ | (1ull << t_); \
        u32 lo_ = __builtin_amdgcn_readlane((u32)own_s_, t_); \
        u32 hi_ = __builtin_amdgcn_readlane((u32)(own_s_ >> 32), t_); \
        u64 dw_ = ((u64)hi_ << 32) | (u64)lo_; \
        cur_ &= ~dw_; \
        cur_ &= (t_ == 63) ? 0ull : (~0ull << (t_ + 1)); \
    } \
    if (lane == 0) kept_w[c * CW + (S)] = kept_; \
    { \
        bool me_ = (kept_ >> lane) & 1ull; \
        _Pragma("unroll") \
        for (int w_ = 0; w_ < CW; ++w_) { \
            if (w_ > (S)) { if (me_ && BC[w_]) atomicOr(&state[w_], BC[w_]); } \
        } \
    } \
} while (0)

__global__ void __launch_bounds__(64, 1)
scan_kernel(const u64* __restrict__ dslot, const u64* __restrict__ valid_w,
            const u64* __restrict__ removed_w, u64* __restrict__ kept_w, int c) {
    __shared__ u64 state[CW];
    int lane = threadIdx.x;
    state[lane] = removed_w[c * CW + lane] | ~valid_w[c * CW + lane];

    u64 b0[CW], b1[CW];
    LOADROW(0, b0);

    STEP(0, b0, b1);  STEP(1, b1, b0);  STEP(2, b0, b1);  STEP(3, b1, b0);
    STEP(4, b0, b1);  STEP(5, b1, b0);  STEP(6, b0, b1);  STEP(7, b1, b0);
    STEP(8, b0, b1);  STEP(9, b1, b0);  STEP(10, b0, b1); STEP(11, b1, b0);
    STEP(12, b0, b1); STEP(13, b1, b0); STEP(14, b0, b1); STEP(15, b1, b0);
    STEP(16, b0, b1); STEP(17, b1, b0); STEP(18, b0, b1); STEP(19, b1, b0);
    STEP(20, b0, b1); STEP(21, b1, b0); STEP(22, b0, b1); STEP(23, b1, b0);
    STEP(24, b0, b1); STEP(25, b1, b0); STEP(26, b0, b1); STEP(27, b1, b0);
    STEP(28, b0, b1); STEP(29, b1, b0); STEP(30, b0, b1); STEP(31, b1, b0);
    STEP(32, b0, b1); STEP(33, b1, b0); STEP(34, b0, b1); STEP(35, b1, b0);
    STEP(36, b0, b1); STEP(37, b1, b0); STEP(38, b0, b1); STEP(39, b1, b0);
    STEP(40, b0, b1); STEP(41, b1, b0); STEP(42, b0, b1); STEP(43, b1, b0);
    STEP(44, b0, b1); STEP(45, b1, b0); STEP(46, b0, b1); STEP(47, b1, b0);
    STEP(48, b0, b1); STEP(49, b1, b0); STEP(50, b0, b1); STEP(51, b1, b0);
    STEP(52, b0, b1); STEP(53, b1, b0); STEP(54, b0, b1); STEP(55, b1, b0);
    STEP(56, b0, b1); STEP(57, b1, b0); STEP(58, b0, b1); STEP(59, b1, b0);
    STEP(60, b0, b1); STEP(61, b1, b0); STEP(62, b0, b1); STEP(63, b1, b0);
}

// ---------------- apply chunk's kept boxes to all later candidates ----------------
// grid: (future-groups of 256) x (CHUNK/256 = 16 slices)
__global__ void elim_kernel(const float4* __restrict__ sboxes, const float* __restrict__ sarea,
                            const u64* __restrict__ kept_words, u64* __restrict__ removed_words,
                            int c) {
    __shared__ float4 kb[256];
    __shared__ float ka[256];
    __shared__ u64 kw[4];
    int tid = threadIdx.x;
    int sb = (c << 12) + blockIdx.y * 256;
    kb[tid] = sboxes[sb + tid];
    ka[tid] = sarea[sb + tid];
    if (tid < 4) kw[tid] = kept_words[c * CW + blockIdx.y * 4 + tid];
    __syncthreads();
    int f = ((c + 1) << 12) + blockIdx.x * 256 + tid;
    bool inb = f < N_ANCH;
    float4 bf;
    float af;
    if (inb) { bf = sboxes[f]; af = sarea[f]; }
    else     { bf = make_float4(0.f, 0.f, 0.f, 0.f); af = 0.f; }
    bool sup = false;
#pragma unroll 8
    for (int k = 0; k < 256; ++k) {
        bool kept = (kw[k >> 6] >> (k & 63)) & 1ull;
        sup |= (kept & iou_gt(kb[k], ka[k], bf, af));
    }
    if (sup && inb) atomicOr(&removed_words[f >> 6], 1ull << (f & 63));
}

// ---------------- output ----------------
__global__ void output_kernel(const float4* __restrict__ boxes, const float* __restrict__ score,
                              const int* __restrict__ rankp, const u64* __restrict__ kept_words,
                              float* __restrict__ out) {
    int i = blockIdx.x * 256 + threadIdx.x;
    if (i >= N_ANCH) return;
    int p = rankp[i];
    float m = ((kept_words[p >> 6] >> (p & 63)) & 1ull) ? 1.0f : 0.0f;
    float4 b = boxes[i];
    float s = score[i];
    out[(size_t)i * 5 + 0] = __fmul_rn(b.x, m);
    out[(size_t)i * 5 + 1] = __fmul_rn(b.y, m);
    out[(size_t)i * 5 + 2] = __fmul_rn(b.z, m);
    out[(size_t)i * 5 + 3] = __fmul_rn(b.w, m);
    out[(size_t)i * 5 + 4] = __fmul_rn(s, m);
}

extern "C" void kernel_launch(void* const* d_in, const int* in_sizes, int n_in,
                              void* d_out, int out_size, void* d_ws, size_t ws_size,
                              hipStream_t stream) {
    const float4* loc = (const float4*)d_in[0];
    const float* cls = (const float*)d_in[1];
    char* ws = (char*)d_ws;

    float4* boxes      = (float4*)(ws + 0);        // 196608
    float*  score      = (float*)(ws + 196608);    // 49152
    u32*    key        = (u32*)  (ws + 245760);    // 49152
    float*  area       = (float*)(ws + 294912);    // 49152
    int*    rankp      = (int*)  (ws + 344064);    // 49152
    float4* sboxes     = (float4*)(ws + 393216);   // 196608
    float*  sarea      = (float*)(ws + 589824);    // 49152
    u64*    valid_w    = (u64*)  (ws + 638976);    // 1536
    u64*    removed_w  = (u64*)  (ws + 640512);    // 1536
    u64*    kept_w     = (u64*)  (ws + 642048);    // 1536
    u64*    diag       = (u64*)  (ws + 643584);    // big: 6291456, small: 2097152
    float*  out        = (float*)d_out;

    const size_t need_big = 643584 + (size_t)NCHUNK * SLOTW * 8;  // 6,935,040 B
    bool big = ws_size >= need_big;

    decode_kernel<<<48, 256, 0, stream>>>(loc, cls, boxes, score, key, area, valid_w);
    rank_kernel<<<1536, 256, 0, stream>>>(key, boxes, area, score, rankp, sboxes, sarea, valid_w);

    if (big) {
        diag_all_kernel<<<N_ANCH, 256, 0, stream>>>(sboxes, sarea, diag);
        for (int c = 0; c < NCHUNK; ++c) {
            scan_kernel<<<1, 64, 0, stream>>>(diag + (size_t)c * SLOTW, valid_w, removed_w, kept_w, c);
            if (c + 1 < NCHUNK) {
                int futures = N_ANCH - ((c + 1) << 12);
                dim3 g((futures + 255) / 256, CHUNK / 256);
                elim_kernel<<<g, 256, 0, stream>>>(sboxes, sarea, kept_w, removed_w, c);
            }
        }
    } else {
        diag_one_kernel<<<CHUNK, 256, 0, stream>>>(sboxes, sarea, diag, 0);
        for (int c = 0; c < NCHUNK; ++c) {
            scan_kernel<<<1, 64, 0, stream>>>(diag, valid_w, removed_w, kept_w, c);
            if (c + 1 < NCHUNK) {
                int futures = N_ANCH - ((c + 1) << 12);
                dim3 g((futures + 255) / 256, CHUNK / 256);
                elim_kernel<<<g, 256, 0, stream>>>(sboxes, sarea, kept_w, removed_w, c);
                diag_one_kernel<<<CHUNK, 256, 0, stream>>>(sboxes, sarea, diag, c + 1);
            }
        }
    }

    output_kernel<<<48, 256, 0, stream>>>(boxes, score, rankp, kept_w, out);
}

// Round 7
// 235.476 us; speedup vs baseline: 1.6906x; 1.6906x over previous
//
#include <hip/hip_runtime.h>
#include <stdint.h>

#define N_ANCH 12288
#define NCLS 64
#define TOTW 192              // 64-bit words over all sorted anchors
#define CAPW 192              // max (word,mask) slots per row == TOTW -> no overflow possible

typedef unsigned long long u64;
typedef unsigned int u32;
typedef unsigned char u8;

// IoU > 0.5 predicate, replicating numpy op order/rounding exactly (no FMA contraction).
__device__ __forceinline__ bool iou_gt(float4 a, float fa, float4 b, float fb) {
    float xx1 = fmaxf(a.x, b.x);
    float yy1 = fmaxf(a.y, b.y);
    float xx2 = fminf(a.z, b.z);
    float yy2 = fminf(a.w, b.w);
    float dx = fmaxf(__fsub_rn(xx2, xx1), 0.0f);
    float dy = fmaxf(__fsub_rn(yy2, yy1), 0.0f);
    float inter = __fmul_rn(dx, dy);
    float denom = __fadd_rn(__fsub_rn(__fadd_rn(fa, fb), inter), 1e-9f);
    float iou = __fdiv_rn(inter, denom);
    return iou > 0.5f;
}

// ---------------- decode: boxes, score, sortable key, area (+ zero valid/kept/wcnt) ----------------
__global__ void decode_kernel(const float4* __restrict__ loc, const float* __restrict__ cls,
                              float4* __restrict__ boxes, float* __restrict__ score,
                              u32* __restrict__ key, float* __restrict__ area,
                              u64* __restrict__ zbase) {
    int i = blockIdx.x * 256 + threadIdx.x;
    if (i < 6528) zbase[i] = 0ull;   // valid_w(192) + kept_w(192) + wcnt(12288 u32 = 6144 u64)
    if (i >= N_ANCH) return;
    float4 l = loc[i];
    int y = i >> 7;        // FM_W = 128
    int x = i & 127;
    float cx = (x + 0.5f) * 8.0f;   // exact
    float cy = (y + 0.5f) * 8.0f;   // exact
    float px = __fadd_rn(__fmul_rn(l.x, 32.0f), cx);
    float py = __fadd_rn(__fmul_rn(l.y, 32.0f), cy);
    float pw = __fmul_rn(expf(l.z), 32.0f);
    float ph = __fmul_rn(expf(l.w), 32.0f);
    float hx = __fmul_rn(pw, 0.5f);
    float hy = __fmul_rn(ph, 0.5f);
    float x1 = __fsub_rn(px, hx), y1 = __fsub_rn(py, hy);
    float x2 = __fadd_rn(px, hx), y2 = __fadd_rn(py, hy);
    float4 b; b.x = x1; b.y = y1; b.z = x2; b.w = y2;
    boxes[i] = b;
    area[i] = __fmul_rn(__fsub_rn(x2, x1), __fsub_rn(y2, y1));

    const float4* cr = (const float4*)(cls + (size_t)i * NCLS);
    float mx = -INFINITY;
#pragma unroll
    for (int k = 0; k < 16; ++k) {
        float4 v = cr[k];
        mx = fmaxf(mx, fmaxf(fmaxf(v.x, v.y), fmaxf(v.z, v.w)));
    }
    float s;
    if (mx >= 0.0f) {
        float e = expf(-mx);
        s = __fdiv_rn(1.0f, __fadd_rn(1.0f, e));
    } else {
        float e = expf(mx);
        s = __fdiv_rn(e, __fadd_rn(1.0f, e));
    }
    score[i] = s;
    float se = (s > 0.5f) ? s : -INFINITY;   // score_eff
    u32 u = __float_as_uint(se);
    u = (u & 0x80000000u) ? ~u : (u | 0x80000000u);   // ascending-ordered uint
    key[i] = u;
}

// ---------------- rank sort: stable descending argsort via O(N^2) rank ----------------
__global__ void rank_kernel(const u32* __restrict__ key, const float4* __restrict__ boxes,
                            const float* __restrict__ area, const float* __restrict__ score,
                            int* __restrict__ rankp, float4* __restrict__ sboxes,
                            float* __restrict__ sarea, u64* __restrict__ valid_words) {
    int tid = threadIdx.x;
    int part = tid & 31;
    int row = blockIdx.x * 8 + (tid >> 5);
    u32 ki = key[row];
    const uint4* kp = (const uint4*)key;
    int r = 0;
#pragma unroll 8
    for (int q = 0; q < 96; ++q) {           // 96*32 = 3072 uint4 = 12288 keys
        uint4 v = kp[(q << 5) + part];
        int j0 = (q << 7) + (part << 2);
        r += (int)(v.x > ki) + (int)((v.x == ki) & (j0 + 0 < row));
        r += (int)(v.y > ki) + (int)((v.y == ki) & (j0 + 1 < row));
        r += (int)(v.z > ki) + (int)((v.z == ki) & (j0 + 2 < row));
        r += (int)(v.w > ki) + (int)((v.w == ki) & (j0 + 3 < row));
    }
    r += __shfl_xor(r, 1);
    r += __shfl_xor(r, 2);
    r += __shfl_xor(r, 4);
    r += __shfl_xor(r, 8);
    r += __shfl_xor(r, 16);
    if (part == 0) {
        rankp[row] = r;
        sboxes[r] = boxes[row];
        sarea[r] = area[row];
        if (score[row] > 0.5f) atomicOr(&valid_words[r >> 6], 1ull << (r & 63));
    }
}

// ---------------- pairs: sparse per-row (word, mask) suppression lists ----------------
// grid (48, 192): block = rows rg*64..+63 vs words 4wg..4wg+3. Each thread owns one (row, word).
__global__ void pairs_kernel(const float4* __restrict__ sboxes, const float* __restrict__ sarea,
                             u32* __restrict__ wcnt, u8* __restrict__ wlist,
                             u64* __restrict__ blist) {
    int wg = blockIdx.x, rg = blockIdx.y;
    if (4 * wg + 3 < rg) return;            // strictly lower-triangle tile
    __shared__ float4 rbox[64];  __shared__ float rarea[64];
    __shared__ float4 qbox[256]; __shared__ float qarea[256];
    int tid = threadIdx.x;
    if (tid < 64) { rbox[tid] = sboxes[rg * 64 + tid]; rarea[tid] = sarea[rg * 64 + tid]; }
    int qg = wg * 256 + tid;
    qbox[tid] = sboxes[qg];
    qarea[tid] = sarea[qg];
    __syncthreads();
    int row = tid >> 2;
    int wloc = tid & 3;
    int W = 4 * wg + wloc;
    if (W < rg) return;
    int p = rg * 64 + row;
    float4 bi = rbox[row];
    float ai = rarea[row];
    u64 mask = 0;
    int qb = wloc << 6;
#pragma unroll 8
    for (int j = 0; j < 64; ++j) {
        bool pred = iou_gt(bi, ai, qbox[qb + j], qarea[qb + j]);
        mask |= ((u64)pred) << j;
    }
    if (W == rg) mask &= (row == 63) ? 0ull : (~0ull << (row + 1));   // q > p within own word
    if (mask) {
        u32 slot = atomicAdd(&wcnt[p], 1u);   // slot < 192 guaranteed (<=192-rg words exist)
        wlist[(size_t)p * CAPW + slot] = (u8)W;
        blist[(size_t)p * CAPW + slot] = mask;
    }
}

// ---------------- global serial greedy scan: ONE wave, 192 word-steps, LDS alive ----------------
__global__ void __launch_bounds__(64, 1)
scan_kernel(const u32* __restrict__ wcnt, const u8* __restrict__ wlist,
            const u64* __restrict__ blist, const u64* __restrict__ valid_w,
            u64* __restrict__ kept_w) {
    __shared__ u64 alive[TOTW];
    int lane = threadIdx.x;
#pragma unroll
    for (int k = 0; k < 3; ++k) alive[lane + 64 * k] = valid_w[lane + 64 * k];

    u32 wcA, wcB, wcC, wcD;
    u64 wrA, wrB, wrC, wrD;
    ulonglong2 bA[4], bB[4], bC[4], bD[4];

#define PREF(S, WC, WR, BB) do { \
    int r_ = (S) * 64 + lane; \
    WC = wcnt[r_]; \
    WR = *(const u64*)&wlist[(size_t)r_ * CAPW]; \
    const ulonglong2* bp_ = (const ulonglong2*)&blist[(size_t)r_ * CAPW]; \
    BB[0] = bp_[0]; BB[1] = bp_[1]; BB[2] = bp_[2]; BB[3] = bp_[3]; \
} while (0)

    PREF(0, wcA, wrA, bA); PREF(1, wcB, wrB, bB);
    PREF(2, wcC, wrC, bC); PREF(3, wcD, wrD, bD);

#define STEPS(S, WC, WR, BB) do { \
    int S_ = (S); \
    int r_ = S_ * 64 + lane; \
    u32 wc_ = WC; u64 wr_ = WR; \
    u64 bv0_ = BB[0].x, bv1_ = BB[0].y, bv2_ = BB[1].x, bv3_ = BB[1].y; \
    u64 bv4_ = BB[2].x, bv5_ = BB[2].y, bv6_ = BB[3].x, bv7_ = BB[3].y; \
    u64 own_s_ = 0; \
    own_s_ |= (wc_ > 0 && (u32)((wr_ >>  0) & 0xFF) == (u32)S_) ? bv0_ : 0ull; \
    own_s_ |= (wc_ > 1 && (u32)((wr_ >>  8) & 0xFF) == (u32)S_) ? bv1_ : 0ull; \
    own_s_ |= (wc_ > 2 && (u32)((wr_ >> 16) & 0xFF) == (u32)S_) ? bv2_ : 0ull; \
    own_s_ |= (wc_ > 3 && (u32)((wr_ >> 24) & 0xFF) == (u32)S_) ? bv3_ : 0ull; \
    own_s_ |= (wc_ > 4 && (u32)((wr_ >> 32) & 0xFF) == (u32)S_) ? bv4_ : 0ull; \
    own_s_ |= (wc_ > 5 && (u32)((wr_ >> 40) & 0xFF) == (u32)S_) ? bv5_ : 0ull; \
    own_s_ |= (wc_ > 6 && (u32)((wr_ >> 48) & 0xFF) == (u32)S_) ? bv6_ : 0ull; \
    own_s_ |= (wc_ > 7 && (u32)((wr_ >> 56) & 0xFF) == (u32)S_) ? bv7_ : 0ull; \
    if (wc_ > 8) { \
        u32 we_ = (wc_ < (u32)CAPW) ? wc_ : (u32)CAPW; \
        for (u32 k_ = 8; k_ < we_; ++k_) { \
            u32 w_ = wlist[(size_t)r_ * CAPW + k_]; \
            if (w_ == (u32)S_) own_s_ |= blist[(size_t)r_ * CAPW + k_]; \
        } \
    } \
    u64 suppmask_ = __ballot(own_s_ != 0ull); \
    u64 cur_ = alive[S_]; \
    u64 kept_ = 0; \
    while (true) { \
        u64 m_ = cur_ & suppmask_; \
        if (m_ == 0) { kept_ |= cur_; break; } \
        int t_ = __ffsll(m_) - 1; \
        u64 below_ = (t_ == 0) ? 0ull : (cur_ & ((1ull << t_) - 1ull)); \
        kept_ |= below_ | (1ull << t_); \
        u32 lo_ = __builtin_amdgcn_readlane((u32)own_s_, t_); \
        u32 hi_ = __builtin_amdgcn_readlane((u32)(own_s_ >> 32), t_); \
        u64 dw_ = ((u64)hi_ << 32) | (u64)lo_; \
        cur_ &= ~dw_; \
        cur_ &= (t_ == 63) ? 0ull : (~0ull << (t_ + 1)); \
    } \
    if (lane == 0) kept_w[S_] = kept_; \
    bool me_ = (kept_ >> lane) & 1ull; \
    if (me_) { \
        u32 w_; \
        w_ = (u32)((wr_ >>  0) & 0xFF); if (wc_ > 0 && w_ > (u32)S_ && bv0_) atomicAnd(&alive[w_], ~bv0_); \
        w_ = (u32)((wr_ >>  8) & 0xFF); if (wc_ > 1 && w_ > (u32)S_ && bv1_) atomicAnd(&alive[w_], ~bv1_); \
        w_ = (u32)((wr_ >> 16) & 0xFF); if (wc_ > 2 && w_ > (u32)S_ && bv2_) atomicAnd(&alive[w_], ~bv2_); \
        w_ = (u32)((wr_ >> 24) & 0xFF); if (wc_ > 3 && w_ > (u32)S_ && bv3_) atomicAnd(&alive[w_], ~bv3_); \
        w_ = (u32)((wr_ >> 32) & 0xFF); if (wc_ > 4 && w_ > (u32)S_ && bv4_) atomicAnd(&alive[w_], ~bv4_); \
        w_ = (u32)((wr_ >> 40) & 0xFF); if (wc_ > 5 && w_ > (u32)S_ && bv5_) atomicAnd(&alive[w_], ~bv5_); \
        w_ = (u32)((wr_ >> 48) & 0xFF); if (wc_ > 6 && w_ > (u32)S_ && bv6_) atomicAnd(&alive[w_], ~bv6_); \
        w_ = (u32)((wr_ >> 56) & 0xFF); if (wc_ > 7 && w_ > (u32)S_ && bv7_) atomicAnd(&alive[w_], ~bv7_); \
        if (wc_ > 8) { \
            u32 we_ = (wc_ < (u32)CAPW) ? wc_ : (u32)CAPW; \
            for (u32 k_ = 8; k_ < we_; ++k_) { \
                u32 w2_ = wlist[(size_t)r_ * CAPW + k_]; \
                if (w2_ > (u32)S_) { \
                    u64 b_ = blist[(size_t)r_ * CAPW + k_]; \
                    if (b_) atomicAnd(&alive[w2_], ~b_); \
                } \
            } \
        } \
    } \
    if (S_ + 4 < TOTW) PREF(S_ + 4, WC, WR, BB); \
} while (0)

    for (int sb = 0; sb < TOTW; sb += 4) {
        STEPS(sb + 0, wcA, wrA, bA);
        STEPS(sb + 1, wcB, wrB, bB);
        STEPS(sb + 2, wcC, wrC, bC);
        STEPS(sb + 3, wcD, wrD, bD);
    }
}

// ---------------- output ----------------
__global__ void output_kernel(const float4* __restrict__ boxes, const float* __restrict__ score,
                              const int* __restrict__ rankp, const u64* __restrict__ kept_words,
                              float* __restrict__ out) {
    int i = blockIdx.x * 256 + threadIdx.x;
    if (i >= N_ANCH) return;
    int p = rankp[i];
    float m = ((kept_words[p >> 6] >> (p & 63)) & 1ull) ? 1.0f : 0.0f;
    float4 b = boxes[i];
    float s = score[i];
    out[(size_t)i * 5 + 0] = __fmul_rn(b.x, m);
    out[(size_t)i * 5 + 1] = __fmul_rn(b.y, m);
    out[(size_t)i * 5 + 2] = __fmul_rn(b.z, m);
    out[(size_t)i * 5 + 3] = __fmul_rn(b.w, m);
    out[(size_t)i * 5 + 4] = __fmul_rn(s, m);
}

extern "C" void kernel_launch(void* const* d_in, const int* in_sizes, int n_in,
                              void* d_out, int out_size, void* d_ws, size_t ws_size,
                              hipStream_t stream) {
    const float4* loc = (const float4*)d_in[0];
    const float* cls = (const float*)d_in[1];
    char* ws = (char*)d_ws;

    float4* boxes   = (float4*)(ws + 0);         // 196608
    float*  score   = (float*) (ws + 196608);    // 49152
    u32*    key     = (u32*)   (ws + 245760);    // 49152
    float*  area    = (float*) (ws + 294912);    // 49152
    int*    rankp   = (int*)   (ws + 344064);    // 49152
    float4* sboxes  = (float4*)(ws + 393216);    // 196608
    float*  sarea   = (float*) (ws + 589824);    // 49152
    u64*    valid_w = (u64*)   (ws + 638976);    // 1536
    u64*    kept_w  = (u64*)   (ws + 640512);    // 1536
    u32*    wcnt    = (u32*)   (ws + 642048);    // 49152
    u8*     wlist   = (u8*)    (ws + 691200);    // 12288*192   = 2359296
    u64*    blist   = (u64*)   (ws + 3050496);   // 12288*192*8 = 18874368 (end ~21.9 MB; ws is 256 MB)
    float*  out     = (float*)d_out;

    decode_kernel<<<48, 256, 0, stream>>>(loc, cls, boxes, score, key, area, valid_w);
    rank_kernel<<<1536, 256, 0, stream>>>(key, boxes, area, score, rankp, sboxes, sarea, valid_w);
    pairs_kernel<<<dim3(48, 192), 256, 0, stream>>>(sboxes, sarea, wcnt, wlist, blist);
    scan_kernel<<<1, 64, 0, stream>>>(wcnt, wlist, blist, valid_w, kept_w);
    output_kernel<<<48, 256, 0, stream>>>(boxes, score, rankp, kept_w, out);
}